// Round 10
// baseline (281.965 us; speedup 1.0000x reference)
//
#include <hip/hip_runtime.h>
#include <stdint.h>

#define N_NODES 100000
#define N_EDGES 1600000
#define IN_DIM 32
#define OUT_DIM 64
#define N_REL 8
#define NSEG (N_NODES * N_REL)     // 800000
#define EPS 1e-10f
#define N_KK 9                      // K-tiles of 32 (8 rel + 1 self)
#define SWG_ELEMS (N_KK * 4 * 64 * 8)  // 18432 bf16 in b-frag order
#define XB_PAIRS (N_NODES * 16)     // 1.6M bf16-pair dwords
#define NTILES ((N_NODES + 63) / 64)   // 1563

typedef __attribute__((ext_vector_type(8))) short bf16x8;
typedef __attribute__((ext_vector_type(2))) short bf16x2;
typedef __attribute__((ext_vector_type(4))) float f32x4;

static __device__ __forceinline__ float bflo(uint32_t u) { return __uint_as_float(u << 16); }
static __device__ __forceinline__ float bfhi(uint32_t u) { return __uint_as_float(u & 0xffff0000u); }
static __device__ __forceinline__ uint16_t f2bf(float f) {
    uint32_t u = __float_as_uint(f);
    return (uint16_t)((u + 0x7fffu + ((u >> 16) & 1u)) >> 16); // RNE
}

// Packed bf16x2 atomic add (gfx950 global_atomic_pk_add_bf16); CAS fallback.
static __device__ __forceinline__ void pk_add_bf16(uint32_t* addr, float f0, float f1) {
#if __has_builtin(__builtin_amdgcn_global_atomic_fadd_v2bf16)
    bf16x2 v;
    v[0] = (short)f2bf(f0);
    v[1] = (short)f2bf(f1);
    __builtin_amdgcn_global_atomic_fadd_v2bf16((bf16x2*)addr, v);
#else
    uint32_t old = *addr, assumed;
    do {
        assumed = old;
        float lo = bflo(assumed) + f0;
        float hi = bfhi(assumed) + f1;
        uint32_t nv = (uint32_t)f2bf(lo) | ((uint32_t)f2bf(hi) << 16);
        old = atomicCAS(addr, assumed, nv);
    } while (old != assumed);
#endif
}

// ---------------------------------------------------------------------------
// Dtype probe (round-3 proved fp32; kept for robustness, ~3us).
// ---------------------------------------------------------------------------
__global__ __launch_bounds__(256) void detect_kernel(const uint32_t* __restrict__ xw,
                                                     int* __restrict__ flag) {
    __shared__ int cnt;
    if (threadIdx.x == 0) cnt = 0;
    __syncthreads();
    int c = 0;
    for (int k = threadIdx.x; k < 4096; k += 256) {
        uint32_t w = xw[k];
        uint32_t e = (w >> 7) & 0xffu;
        c += (e >= 160u) ? 1 : 0;
    }
    atomicAdd(&cnt, c);
    __syncthreads();
    if (threadIdx.x == 0) *flag = (cnt > 64) ? 1 : 0;  // 1 = fp32 inputs
}

// ---------------------------------------------------------------------------
// prep: (a) xb = x as bf16 pairs (halves the per-edge gather: 128B->64B);
//       (b) sWg = [Wl;Ws] swizzled to b-frag order; (c) biasv = bl+bs.
// ---------------------------------------------------------------------------
__global__ __launch_bounds__(256) void prep_kernel(const void* __restrict__ x,
                                                   const void* __restrict__ Wl,
                                                   const void* __restrict__ Ws,
                                                   const void* __restrict__ bl,
                                                   const void* __restrict__ bs,
                                                   const int* __restrict__ flag,
                                                   uint32_t* __restrict__ xb,
                                                   uint16_t* __restrict__ sWg,
                                                   float* __restrict__ biasv) {
    int f32 = *flag;
    int idx = blockIdx.x * 256 + threadIdx.x;
    if (idx < XB_PAIRS) {
        if (f32) {
            float2 v = ((const float2*)x)[idx];
            xb[idx] = (uint32_t)f2bf(v.x) | ((uint32_t)f2bf(v.y) << 16);
        } else {
            xb[idx] = ((const uint32_t*)x)[idx];
        }
    } else if (idx < XB_PAIRS + SWG_ELEMS) {
        int w = idx - XB_PAIRS;
        int j    = w & 7;
        int lane = (w >> 3) & 63;
        int ot   = (w >> 9) & 3;
        int kk   = w >> 11;
        int quad = lane >> 4;
        int k = kk * 32 + quad * 8 + j;
        int o = ot * 16 + (lane & 15);
        if (f32) {
            float v = (k < 256) ? ((const float*)Wl)[(size_t)k * OUT_DIM + o]
                                : ((const float*)Ws)[(size_t)(k - 256) * OUT_DIM + o];
            sWg[w] = f2bf(v);
        } else {
            sWg[w] = (k < 256) ? ((const uint16_t*)Wl)[(size_t)k * OUT_DIM + o]
                               : ((const uint16_t*)Ws)[(size_t)(k - 256) * OUT_DIM + o];
        }
    } else if (idx < XB_PAIRS + SWG_ELEMS + OUT_DIM) {
        int o = idx - XB_PAIRS - SWG_ELEMS;
        if (f32) biasv[o] = ((const float*)bl)[o] + ((const float*)bs)[o];
        else     biasv[o] = bflo((uint32_t)((const uint16_t*)bl)[o])
                          + bflo((uint32_t)((const uint16_t*)bs)[o]);
    }
}

// ---------------------------------------------------------------------------
// Scatter with packed-bf16 atomics: 16 lanes per edge, lane = feature pair.
// Gathers from xb (bf16): 64B per edge (was 128B fp32). 25.6M pk atomics.
// ---------------------------------------------------------------------------
__global__ __launch_bounds__(256) void scatter_pk_kernel(
    const int* __restrict__ el,
    const void* __restrict__ ew,
    const uint32_t* __restrict__ xb,
    const int* __restrict__ flag,
    uint32_t* __restrict__ num,   // NSEG * 16 dwords (bf16 pairs)
    float* __restrict__ den)
{
    int t = blockIdx.x * 256 + threadIdx.x;
    int e = t >> 4;
    int p = t & 15;                // feature-pair index
    if (e >= N_EDGES) return;

    int src = el[e * 3 + 0];
    int dst = el[e * 3 + 1];
    int rel = el[e * 3 + 2];

    float w = (*flag) ? ((const float*)ew)[e]
                      : bflo((uint32_t)((const uint16_t*)ew)[e]);

    uint32_t d = xb[(size_t)src * 16 + p];
    int seg = dst * N_REL + rel;
    pk_add_bf16(&num[(size_t)seg * 16 + p], w * bflo(d), w * bfhi(d));
    if (p == 0) atomicAdd(&den[seg], w);
}

// ---------------------------------------------------------------------------
// Dense MFMA GEMM, grid-strided over 64-node tiles (LDS staged ONCE/block):
//   C[100000x64] = [num/(den+eps) | xb] * W + bias, relu.
// MFMA layouts (HW-verified): A[m=lane&15][k=quad*8+j]; B[k][n=lane&15];
// C row=quad*4+reg, col=lane&15.
// ---------------------------------------------------------------------------
__global__ __launch_bounds__(256) void dense_mfma_kernel(
    const uint32_t* __restrict__ num,
    const float* __restrict__ den,
    const uint32_t* __restrict__ xb,
    const uint16_t* __restrict__ sWg,
    const float* __restrict__ biasv,
    const int* __restrict__ flag,
    void* __restrict__ out)
{
    __shared__ uint16_t sB[SWG_ELEMS]; // 36KB
    #pragma unroll
    for (int it = 0; it < SWG_ELEMS / (256 * 8); ++it) {   // 9 iterations
        int idx = (it * 256 + threadIdx.x) * 8;
        *(bf16x8*)(sB + idx) = *(const bf16x8*)(sWg + idx);
    }
    __syncthreads();

    int f32  = *flag;
    int wid  = threadIdx.x >> 6;
    int lane = threadIdx.x & 63;
    int quad = lane >> 4;
    int m    = lane & 15;

    float bias[4];
    #pragma unroll
    for (int ot = 0; ot < 4; ++ot) bias[ot] = biasv[ot * 16 + m];

    for (int tile = blockIdx.x; tile < NTILES; tile += gridDim.x) {
        int n0 = tile * 64 + wid * 16;
        int n  = n0 + m;
        int nc = (n < N_NODES) ? n : (N_NODES - 1);

        // den row as two float4 loads (was 8 scalar loads)
        float4 d0 = *(const float4*)(den + (size_t)nc * 8);
        float4 d1 = *(const float4*)(den + (size_t)nc * 8 + 4);
        float inv[8];
        inv[0] = 1.0f / (d0.x + EPS); inv[1] = 1.0f / (d0.y + EPS);
        inv[2] = 1.0f / (d0.z + EPS); inv[3] = 1.0f / (d0.w + EPS);
        inv[4] = 1.0f / (d1.x + EPS); inv[5] = 1.0f / (d1.y + EPS);
        inv[6] = 1.0f / (d1.z + EPS); inv[7] = 1.0f / (d1.w + EPS);

        f32x4 acc[4];
        #pragma unroll
        for (int ot = 0; ot < 4; ++ot) acc[ot] = (f32x4){0.f, 0.f, 0.f, 0.f};

        #pragma unroll
        for (int kk = 0; kk < N_KK; ++kk) {
            bf16x8 a;
            if (kk < 8) {
                const uint4 d = *(const uint4*)(num + ((size_t)nc * 8 + kk) * 16 + quad * 4);
                float iv = inv[kk];
                a[0] = (short)f2bf(bflo(d.x) * iv); a[1] = (short)f2bf(bfhi(d.x) * iv);
                a[2] = (short)f2bf(bflo(d.y) * iv); a[3] = (short)f2bf(bfhi(d.y) * iv);
                a[4] = (short)f2bf(bflo(d.z) * iv); a[5] = (short)f2bf(bfhi(d.z) * iv);
                a[6] = (short)f2bf(bflo(d.w) * iv); a[7] = (short)f2bf(bfhi(d.w) * iv);
            } else {
                a = *(const bf16x8*)((const uint16_t*)xb + (size_t)nc * IN_DIM + quad * 8);
            }
            #pragma unroll
            for (int ot = 0; ot < 4; ++ot) {
                bf16x8 b = *(const bf16x8*)(sB + ((kk * 4 + ot) * 64 + lane) * 8);
                acc[ot] = __builtin_amdgcn_mfma_f32_16x16x32_bf16(a, b, acc[ot], 0, 0, 0);
            }
        }

        #pragma unroll
        for (int ot = 0; ot < 4; ++ot) {
            #pragma unroll
            for (int reg = 0; reg < 4; ++reg) {
                int node = n0 + quad * 4 + reg;
                if (node >= N_NODES) continue;
                int o = ot * 16 + m;
                float v = fmaxf(acc[ot][reg] + bias[ot], 0.0f);
                if (f32) ((float*)out)[(size_t)node * OUT_DIM + o] = v;
                else     ((uint16_t*)out)[(size_t)node * OUT_DIM + o] = f2bf(v);
            }
        }
    }
}

// ===========================================================================
extern "C" void kernel_launch(void* const* d_in, const int* in_sizes, int n_in,
                              void* d_out, int out_size, void* d_ws, size_t ws_size,
                              hipStream_t stream) {
    const void* x  = d_in[0];
    const int* el  = (const int*)d_in[1];
    const void* ew = d_in[2];
    const void* Wl = d_in[3];
    const void* bl = d_in[4];
    const void* Ws = d_in[5];
    const void* bs = d_in[6];

    // ws: [flag 64B][den 3.2MB][num 51.2MB][sWg 36KB][biasv 256B][xb 6.4MB]
    const size_t OFF_DEN  = 64;
    const size_t OFF_NUM  = OFF_DEN + (size_t)NSEG * 4;
    const size_t OFF_SWG  = OFF_NUM + (size_t)NSEG * IN_DIM * 2;
    const size_t OFF_BIAS = OFF_SWG + (size_t)SWG_ELEMS * 2;
    const size_t OFF_XB   = OFF_BIAS + OUT_DIM * 4;
    const size_t REQ      = OFF_XB + (size_t)XB_PAIRS * 4;   // ~61MB
    if (ws_size < REQ) return; // round-4 evidence: ws >= 105.6MB

    int*      flag  = (int*)d_ws;
    float*    den   = (float*)((char*)d_ws + OFF_DEN);
    uint32_t* num   = (uint32_t*)((char*)d_ws + OFF_NUM);
    uint16_t* sWg   = (uint16_t*)((char*)d_ws + OFF_SWG);
    float*    biasv = (float*)((char*)d_ws + OFF_BIAS);
    uint32_t* xb    = (uint32_t*)((char*)d_ws + OFF_XB);

    hipMemsetAsync(d_ws, 0, OFF_SWG, stream);  // flag+den+num (bf16 zero == 0)
    detect_kernel<<<1, 256, 0, stream>>>((const uint32_t*)x, flag);
    {
        int total = XB_PAIRS + SWG_ELEMS + OUT_DIM;
        prep_kernel<<<(total + 255) / 256, 256, 0, stream>>>(x, Wl, Ws, bl, bs, flag, xb, sWg, biasv);
    }
    {
        long long threads = (long long)N_EDGES * 16;
        int blocks = (int)((threads + 255) / 256);  // 100000
        scatter_pk_kernel<<<blocks, 256, 0, stream>>>(el, ew, xb, flag, num, den);
    }
    dense_mfma_kernel<<<1024, 256, 0, stream>>>(num, den, xb, sWg, biasv, flag, d_out);
}